// Round 8
// baseline (190.108 us; speedup 1.0000x reference)
//
#include <hip/hip_runtime.h>
#include <hip/hip_fp16.h>

// Ensemble MLP: E=8, B=16384, DS=32, DA=8, H=128, din=40 (padded to 64 for K).
// preds[i,j,b,:] = MLP_j(inp[i,b,:]); out0 = mean_i(preds)+states, out1 = var_i(preds, ddof=1)
//
// R16 = R15 with the sIn staging leg ELIMINATED (LDS-pipe relief):
// - Budget analysis: per-CU LDS traffic = 12 waves x 2.67 tiles x 8 i x 41KB
//   ~ 10.5MB ~ 65% of kernel cycles at measured b128 rate => LDS pipe is the
//   top pipe (MFMA 38%, VALU 29%). Occupancy is capped at 12 waves/CU
//   (R9/R10/R14: 4 blocks/CU needs VGPR<=64 = spill trap), so cut LDS traffic.
// - States: REGISTER prefetch (32 VGPRs): loads for i+1 issued at L1-start,
//   cvt_pkrtz at next L0 => ~800cy of L1+L2 MFMA hides latency (R14's mistake
//   was loading inside L0 with no distance).
// - Actions: 1KB sAct buffer (64 rows x 8 f16), staged per-i by wave 0
//   (loads at L1-start, pack+store after L1 compute, fenced by B3). L0 reads
//   are 4-lane same-address broadcasts (~free banks); q>=1 lanes get zeros
//   via cndmask (W0 rows 40..63 are zero, so this is exact — R14 proved it).
// - Deletes sIn (8KB), zero-fill, staging blocks: 41 -> 32 KB LDS/wave/i
//   (-21%); LDS 40960 -> 33792 B.
// Kept from R15/R12: f16 MFMA datapath + packed lrelu, grid 768 = 3 blocks/CU
// one generation, persistent blocks with resident weight fragments,
// bias-as-acc-init, XOR-swizzled sHa/sHb, weights-as-A for L0/L1 with packed
// b64 hidden stores, R4-orientation L2, deferred b2 algebra, setprio around
// MFMA clusters (neutral but harmless).

#define NE 8
#define NB 16384
#define DS 32
#define DA 8
#define HH 128
#define DIN 40
#define BT 64            // batch rows per block-tile
#define NSLOT 96         // bt slots (grid = 8*NSLOT = 768 = 3/CU)
#define SLOPE 0.01f

using h16x8 = __attribute__((ext_vector_type(8))) _Float16;
using f16x2 = __attribute__((ext_vector_type(2))) _Float16;
using f32x4 = __attribute__((ext_vector_type(4))) float;

// cvt_pkrtz returns ext_vector(2) of __fp16 on this toolchain; bit-cast to
// _Float16x2 so subsequent arithmetic stays packed (no float promotion).
__device__ __forceinline__ f16x2 cvtpk(float a, float b) {
    auto r = __builtin_amdgcn_cvt_pkrtz(a, b);
    union { decltype(r) i; f16x2 o; } cv; cv.i = r; return cv.o;
}

// pack 8 f32 (two float4) -> h16x8 via 4x v_cvt_pkrtz
__device__ __forceinline__ h16x8 pack8(float4 a, float4 b) {
    union { f16x2 h[4]; h16x8 v; } u;
    u.h[0] = cvtpk(a.x, a.y); u.h[1] = cvtpk(a.z, a.w);
    u.h[2] = cvtpk(b.x, b.y); u.h[3] = cvtpk(b.z, b.w);
    return u.v;
}

// pack 2 f32 -> 2 f16 with packed leaky-relu: cvt_pkrtz + pk_mul + pk_max
__device__ __forceinline__ unsigned int pklr(float a, float b) {
    f16x2 z = cvtpk(a, b);
    f16x2 s = z * (_Float16)SLOPE;              // v_pk_mul_f16
    f16x2 r = __builtin_elementwise_max(z, s);  // v_pk_max_f16
    union { f16x2 h; unsigned int u; } cv; cv.h = r; return cv.u;
}

// Swizzled element index (16B blocks of 8 f16; block' = block ^ row-bits)
__device__ __forceinline__ int sh_idx(int row, int kb) {           // 128 elts/row
    return row * 128 + ((kb ^ (row & 15)) << 3);
}

__global__ __launch_bounds__(256, 3)
void ens_mlp_kernel(const float* __restrict__ states,
                    const float* __restrict__ actions,
                    const float* __restrict__ W0g,
                    const float* __restrict__ b0g,
                    const float* __restrict__ W1g,
                    const float* __restrict__ b1g,
                    const float* __restrict__ W2g,
                    const float* __restrict__ b2g,
                    float* __restrict__ out)
{
    __shared__ __align__(16) unsigned short sAct[BT * 8];     //  1 KB
    __shared__ __align__(16) unsigned short sHa[BT * 128];    // 16 KB
    __shared__ __align__(16) unsigned short sHb[BT * 128];    // 16 KB  -> 33792 total

    const int j    = blockIdx.x & 7;          // j fast-varying
    const int slot = blockIdx.x >> 3;         // 0..95
    const int tid  = threadIdx.x;
    const int wave = tid >> 6;
    const int lane = tid & 63;
    const int q    = lane >> 4;
    const int l16  = lane & 15;
    const int fb   = 32 * wave;               // L0/L1: wave owns features fb..fb+31 (A/M dim)
    const int l2m  = 32 * (wave >> 1);        // L2 (R4 orientation): rows l2m..l2m+31
    const int l2n  = 16 * (wave & 1);         //                      cols l2n..l2n+15

    const float* W0j = W0g + j * (DIN * HH);
    const float* W1j = W1g + j * (HH * HH);
    const float* W2j = W2g + j * (HH * DS);

    // ---- L0/L1 weight A-fragments: lane holds W[k = ks*32+q*8+t][feat = base+l16]
    h16x8 w0f[2][2];   // 16 VGPRs (k >= 40 rows zero)
    h16x8 w1f[4][2];   // 32 VGPRs
    h16x8 w2f[4];      // 16 VGPRs (L2 B-frags, R4 orientation)
    f32x4 b0v[2], b1v[2];   // acc-init biases, C-layout (lane owns feats q*4+r)
    float b2s;

    #pragma unroll
    for (int ks = 0; ks < 2; ++ks)
      #pragma unroll
      for (int mt = 0; mt < 2; ++mt) {
        const int n = fb + mt * 16 + l16;
        #pragma unroll
        for (int t = 0; t < 8; ++t) {
          const int k = ks * 32 + q * 8 + t;
          w0f[ks][mt][t] = (_Float16)((k < DIN) ? W0j[k * HH + n] : 0.f);
        }
      }
    #pragma unroll
    for (int ks = 0; ks < 4; ++ks)
      #pragma unroll
      for (int mt = 0; mt < 2; ++mt) {
        const int n = fb + mt * 16 + l16;
        #pragma unroll
        for (int t = 0; t < 8; ++t) {
          const int k = ks * 32 + q * 8 + t;
          w1f[ks][mt][t] = (_Float16)W1j[k * HH + n];
        }
      }
    #pragma unroll
    for (int ks = 0; ks < 4; ++ks) {
        const int n = l2n + l16;
        #pragma unroll
        for (int t = 0; t < 8; ++t) {
          const int k = ks * 32 + q * 8 + t;
          w2f[ks][t] = (_Float16)W2j[k * DS + n];
        }
    }
    #pragma unroll
    for (int mt = 0; mt < 2; ++mt)
      #pragma unroll
      for (int r = 0; r < 4; ++r) {
        b0v[mt][r] = b0g[j * HH + fb + mt * 16 + q * 4 + r];
        b1v[mt][r] = b1g[j * HH + fb + mt * 16 + q * 4 + r];
      }
    b2s = b2g[j * DS + l2n + l16];

    const f32x4 z4 = {0.f, 0.f, 0.f, 0.f};
    h16x8 hz;
    #pragma unroll
    for (int t = 0; t < 8; ++t) hz[t] = (_Float16)0.f;
    const bool qz = (q == 0);

    for (int bt = slot; bt < NB / BT; bt += NSLOT) {
        const int b0 = bt * BT;

        // ---- tile top: stage sAct(i=0) + prefetch states(i=0) into regs.
        // (One exposed load per tile; ~1% of tile time.)
        if (tid < BT) {
            const float4* ap = reinterpret_cast<const float4*>(
                actions + ((size_t)b0 + tid) * DA);
            union { h16x8 v; uint4 u; } pk;
            pk.v = pack8(ap[0], ap[1]);
            *reinterpret_cast<uint4*>(&sAct[tid * 8]) = pk.u;
        }
        float4 sfA[2][2], sfB[2][2];     // states prefetch: 32 VGPRs
        #pragma unroll
        for (int nh = 0; nh < 2; ++nh)
          #pragma unroll
          for (int nt = 0; nt < 2; ++nt) {
            const int row = nh * 32 + nt * 16 + l16;
            const float4* sp = reinterpret_cast<const float4*>(
                states + ((size_t)b0 + row) * DS + q * 8);
            sfA[nh][nt] = sp[0]; sfB[nh][nt] = sp[1];
          }
        __syncthreads();   // B1: sAct(0) visible

        float sa[2][4], sq[2][4];
        #pragma unroll
        for (int mt = 0; mt < 2; ++mt)
          #pragma unroll
          for (int r = 0; r < 4; ++r) { sa[mt][r] = 0.f; sq[mt][r] = 0.f; }

        for (int i = 0; i < NE; ++i) {
            // ---- Layer 0: h0 = lrelu(W0^T inp + b0); B-frags from prefetch
            // regs (states) + sAct broadcast (actions). acc init = b0. ----
            #pragma unroll
            for (int nh = 0; nh < 2; ++nh) {
                h16x8 bf0[2], bf1[2];
                #pragma unroll
                for (int nt = 0; nt < 2; ++nt) {
                    bf0[nt] = pack8(sfA[nh][nt], sfB[nh][nt]);
                    const int row = nh * 32 + nt * 16 + l16;
                    const h16x8 av = *reinterpret_cast<const h16x8*>(&sAct[row * 8]);
                    bf1[nt] = qz ? av : hz;
                }
                f32x4 acc[2][2];
                #pragma unroll
                for (int mt = 0; mt < 2; ++mt)
                  #pragma unroll
                  for (int nt = 0; nt < 2; ++nt) acc[mt][nt] = b0v[mt];
                __builtin_amdgcn_s_setprio(1);
                #pragma unroll
                for (int mt = 0; mt < 2; ++mt)
                  #pragma unroll
                  for (int nt = 0; nt < 2; ++nt) {
                    acc[mt][nt] = __builtin_amdgcn_mfma_f32_16x16x32_f16(
                        w0f[0][mt], bf0[nt], acc[mt][nt], 0, 0, 0);
                    acc[mt][nt] = __builtin_amdgcn_mfma_f32_16x16x32_f16(
                        w0f[1][mt], bf1[nt], acc[mt][nt], 0, 0, 0);
                  }
                __builtin_amdgcn_s_setprio(0);
                // lane holds 4 consecutive features (q*4+r) of batch row nt*16+l16
                #pragma unroll
                for (int mt = 0; mt < 2; ++mt)
                  #pragma unroll
                  for (int nt = 0; nt < 2; ++nt) {
                    const int row = nh * 32 + nt * 16 + l16;
                    const int blk = (fb >> 3) + mt * 2 + (q >> 1);
                    const int idx = sh_idx(row, blk) + (q & 1) * 4;
                    uint2 pk;
                    pk.x = pklr(acc[mt][nt][0], acc[mt][nt][1]);
                    pk.y = pklr(acc[mt][nt][2], acc[mt][nt][3]);
                    *reinterpret_cast<uint2*>(&sHa[idx]) = pk;
                  }
            }
            __syncthreads();   // B2: h0 ready; sAct(i) reads drained

            // ---- issue prefetch loads for i+1 (consumed at next L0; latency
            // hidden under L1+L2 MFMA). Action pack/store deferred to post-L1.
            float4 aA, aB;
            const bool pf = (i < NE - 1);
            if (pf) {
                const float* Sn = states + ((size_t)(i + 1) * NB + b0) * DS;
                if (tid < BT) {
                    const float4* ap = reinterpret_cast<const float4*>(
                        actions + ((size_t)(i + 1) * NB + b0 + tid) * DA);
                    aA = ap[0]; aB = ap[1];
                }
                #pragma unroll
                for (int nh = 0; nh < 2; ++nh)
                  #pragma unroll
                  for (int nt = 0; nt < 2; ++nt) {
                    const int row = nh * 32 + nt * 16 + l16;
                    const float4* sp = reinterpret_cast<const float4*>(
                        Sn + row * DS + q * 8);
                    sfA[nh][nt] = sp[0]; sfB[nh][nt] = sp[1];
                  }
            }

            // ---- Layer 1: h1 = lrelu(W1^T h0 + b1); acc init = b1 ----
            #pragma unroll
            for (int nh = 0; nh < 2; ++nh) {
                f32x4 acc[2][2];
                #pragma unroll
                for (int mt = 0; mt < 2; ++mt)
                  #pragma unroll
                  for (int nt = 0; nt < 2; ++nt) acc[mt][nt] = b1v[mt];
                __builtin_amdgcn_s_setprio(1);
                #pragma unroll
                for (int ks = 0; ks < 4; ++ks) {
                    h16x8 bf[2];
                    #pragma unroll
                    for (int nt = 0; nt < 2; ++nt) {
                        const int row = nh * 32 + nt * 16 + l16;
                        bf[nt] = *(const h16x8*)(&sHa[sh_idx(row, ks * 4 + q)]);
                    }
                    #pragma unroll
                    for (int mt = 0; mt < 2; ++mt)
                      #pragma unroll
                      for (int nt = 0; nt < 2; ++nt)
                        acc[mt][nt] = __builtin_amdgcn_mfma_f32_16x16x32_f16(
                            w1f[ks][mt], bf[nt], acc[mt][nt], 0, 0, 0);
                }
                __builtin_amdgcn_s_setprio(0);
                #pragma unroll
                for (int mt = 0; mt < 2; ++mt)
                  #pragma unroll
                  for (int nt = 0; nt < 2; ++nt) {
                    const int row = nh * 32 + nt * 16 + l16;
                    const int blk = (fb >> 3) + mt * 2 + (q >> 1);
                    const int idx = sh_idx(row, blk) + (q & 1) * 4;
                    uint2 pk;
                    pk.x = pklr(acc[mt][nt][0], acc[mt][nt][1]);
                    pk.y = pklr(acc[mt][nt][2], acc[mt][nt][3]);
                    *reinterpret_cast<uint2*>(&sHb[idx]) = pk;
                  }
            }

            // ---- sAct(i+1) pack+store (action loads landed during L1) ----
            if (pf && tid < BT) {
                union { h16x8 v; uint4 u; } pk;
                pk.v = pack8(aA, aB);
                *reinterpret_cast<uint4*>(&sAct[tid * 8]) = pk.u;
            }
            __syncthreads();   // B3: h1 + sAct(i+1) ready

            // ---- Layer 2 (R4 orientation): A=h1 (m=batch), B=W2 (n=feature) ----
            {
                f32x4 acc2[2];
                acc2[0] = z4; acc2[1] = z4;
                __builtin_amdgcn_s_setprio(1);
                #pragma unroll
                for (int ks = 0; ks < 4; ++ks) {
                    #pragma unroll
                    for (int mt = 0; mt < 2; ++mt) {
                        const int row = l2m + 16 * mt + l16;
                        const h16x8 a2 = *(const h16x8*)(&sHb[sh_idx(row, ks * 4 + q)]);
                        acc2[mt] = __builtin_amdgcn_mfma_f32_16x16x32_f16(
                            a2, w2f[ks], acc2[mt], 0, 0, 0);
                    }
                }
                __builtin_amdgcn_s_setprio(0);
                #pragma unroll
                for (int mt = 0; mt < 2; ++mt)
                  #pragma unroll
                  for (int r = 0; r < 4; ++r) {
                    const float a = acc2[mt][r];      // b2 deferred
                    sa[mt][r] += a;
                    sq[mt][r] = fmaf(a, a, sq[mt][r]);
                  }
            }
        }

        // ---- Epilogue for this bt: sum = sa + 8b; sum(p^2) = sq + 2b*sa + 8b^2
        #pragma unroll
        for (int mt = 0; mt < 2; ++mt)
          #pragma unroll
          for (int r = 0; r < 4; ++r) {
            const int row = l2m + 16 * mt + q * 4 + r;   // batch row (C: row=quad*4+r)
            const int col = l2n + l16;                   // feature
            const size_t o = ((size_t)j * NB + b0 + row) * DS + col;
            const float b  = b2s;
            const float s  = sa[mt][r] + 8.f * b;
            const float s2 = sq[mt][r] + 2.f * b * sa[mt][r] + 8.f * b * b;
            out[o] = s * 0.125f + states[o];
            out[(size_t)NE * NB * DS + o] = (s2 - s * s * 0.125f) * (1.0f / 7.0f);
          }
    }
}

extern "C" void kernel_launch(void* const* d_in, const int* in_sizes, int n_in,
                              void* d_out, int out_size, void* d_ws, size_t ws_size,
                              hipStream_t stream) {
    (void)in_sizes; (void)n_in; (void)d_ws; (void)ws_size; (void)out_size;
    const float* states  = (const float*)d_in[0];
    const float* actions = (const float*)d_in[1];
    const float* W0 = (const float*)d_in[2];
    const float* b0 = (const float*)d_in[3];
    const float* W1 = (const float*)d_in[4];
    const float* b1 = (const float*)d_in[5];
    const float* W2 = (const float*)d_in[6];
    const float* b2 = (const float*)d_in[7];
    float* out = (float*)d_out;
    dim3 grid(8 * NSLOT);   // 768 persistent blocks = 3/CU, one generation
    ens_mlp_kernel<<<grid, dim3(256), 0, stream>>>(states, actions, W0, b0, W1, b1, W2, b2, out);
}

// Round 9
// 144.243 us; speedup vs baseline: 1.3180x; 1.3180x over previous
//
#include <hip/hip_runtime.h>
#include <hip/hip_fp16.h>

// Ensemble MLP: E=8, B=16384, DS=32, DA=8, H=128, din=40 (padded to 64 for K).
// preds[i,j,b,:] = MLP_j(inp[i,b,:]); out0 = mean_i(preds)+states, out1 = var_i(preds, ddof=1)
//
// R17 = re-land of R12 (session best: 145.4us bench / ~76us steady), after
// R13/R14/R16 falsified the remaining structural levers:
// - Occupancy: HARD-CAPPED at 12 waves/CU. 4 blocks/CU needs VGPR<=64 (R9:
//   64->4blk but spills; R10: 80->3blk; R14: 84 + 32KB LDS -> still 3blk);
//   resident weight fragments alone are 64 VGPRs.
// - Register-held inputs: R14 (direct global loads in L0) exposes ~200-900cy
//   load latency; R16 (32-reg prefetch + deferred action pack) spills to
//   scratch (WRITE 33->61MB, FETCH 87->102MB at VGPR_Count=84) -> dur 123us.
//   There is no VGPR headroom for 32+ long-lived prefetch regs.
// - LDS reads are minimal at current reuse (B-frags shared across both mt
//   tiles; more features/wave needs 112+ weight VGPRs = same wall).
// - Barriers minimal (2/i); lrelu/pack VALU minimized (packed f16, verified
//   -20% VALUBusy); setprio neutral (R15); tile balance tweaks neutral.
// Structure: per-wave chain ds_read -> MFMA -> pack -> ds_write -> barrier at
// 3 waves/SIMD; ~780 TF effective = 40% of f16 MFMA ceiling. This is the
// structure's ceiling (MFMA 33 / VALU 30 / LDS ~50-60 / HBM 20, none
// saturated individually; chain-latency bound).
//
// Kernel: f16 MFMA datapath (cvt_pkrtz + v_pk_mul/max packed lrelu), grid
// 768 = 3 blocks/CU one generation, persistent blocks with resident weight
// fragments, bias-as-acc-init, XOR-swizzled unpadded LDS (40960 B),
// vectorized dwordx4 staging with i+1 prefetch overlapped under L1,
// weights-as-A for L0/L1 with packed b64 hidden stores, R4-orientation L2,
// deferred b2 algebra, race-safe prologue ordering.

#define NE 8
#define NB 16384
#define DS 32
#define DA 8
#define HH 128
#define DIN 40
#define BT 64            // batch rows per block-tile
#define NSLOT 96         // bt slots (grid = 8*NSLOT = 768 = 3/CU)
#define SLOPE 0.01f

using h16x8 = __attribute__((ext_vector_type(8))) _Float16;
using f16x2 = __attribute__((ext_vector_type(2))) _Float16;
using f32x4 = __attribute__((ext_vector_type(4))) float;

// cvt_pkrtz returns ext_vector(2) of __fp16 on this toolchain; bit-cast to
// _Float16x2 so subsequent arithmetic stays packed (no float promotion).
__device__ __forceinline__ f16x2 cvtpk(float a, float b) {
    auto r = __builtin_amdgcn_cvt_pkrtz(a, b);
    union { decltype(r) i; f16x2 o; } cv; cv.i = r; return cv.o;
}

// pack 2 f32 -> 2 f16 (RTZ), no activation (staging)
__device__ __forceinline__ unsigned int pkh(float a, float b) {
    union { f16x2 h; unsigned int u; } cv;
    cv.h = cvtpk(a, b);
    return cv.u;
}

// pack 2 f32 -> 2 f16 with packed leaky-relu: cvt_pkrtz + pk_mul + pk_max
__device__ __forceinline__ unsigned int pklr(float a, float b) {
    f16x2 z = cvtpk(a, b);
    f16x2 s = z * (_Float16)SLOPE;              // v_pk_mul_f16
    f16x2 r = __builtin_elementwise_max(z, s);  // v_pk_max_f16
    union { f16x2 h; unsigned int u; } cv; cv.h = r; return cv.u;
}

// Swizzled element indices (16B blocks of 8 f16; block' = block ^ row-bits)
__device__ __forceinline__ int sin_idx(int row, int kb) {          // 64 elts/row
    return row * 64 + ((kb ^ (row & 7)) << 3);
}
__device__ __forceinline__ int sh_idx(int row, int kb) {           // 128 elts/row
    return row * 128 + ((kb ^ (row & 15)) << 3);
}

__global__ __launch_bounds__(256, 3)
void ens_mlp_kernel(const float* __restrict__ states,
                    const float* __restrict__ actions,
                    const float* __restrict__ W0g,
                    const float* __restrict__ b0g,
                    const float* __restrict__ W1g,
                    const float* __restrict__ b1g,
                    const float* __restrict__ W2g,
                    const float* __restrict__ b2g,
                    float* __restrict__ out)
{
    __shared__ __align__(16) unsigned short sIn[BT * 64];     //  8 KB
    __shared__ __align__(16) unsigned short sHa[BT * 128];    // 16 KB
    __shared__ __align__(16) unsigned short sHb[BT * 128];    // 16 KB  -> 40960 total

    const int j    = blockIdx.x & 7;          // j fast-varying
    const int slot = blockIdx.x >> 3;         // 0..95
    const int tid  = threadIdx.x;
    const int wave = tid >> 6;
    const int lane = tid & 63;
    const int q    = lane >> 4;
    const int l16  = lane & 15;
    const int fb   = 32 * wave;               // L0/L1: wave owns features fb..fb+31 (A/M dim)
    const int l2m  = 32 * (wave >> 1);        // L2 (R4 orientation): rows l2m..l2m+31
    const int l2n  = 16 * (wave & 1);         //                      cols l2n..l2n+15

    // zero-fill sIn once (swizzle-invariant); blocks 5..7 stay zero forever
    // (staging only writes blocks 0..4) = K padding cols 40..63.
    {
        uint4 z; z.x = z.y = z.z = z.w = 0u;
        uint4* p = reinterpret_cast<uint4*>(&sIn[tid * 32]);
        p[0] = z; p[1] = z; p[2] = z; p[3] = z;
    }

    const float* W0j = W0g + j * (DIN * HH);
    const float* W1j = W1g + j * (HH * HH);
    const float* W2j = W2g + j * (HH * DS);

    // ---- L0/L1 weight A-fragments: lane holds W[k = ks*32+q*8+t][feat = base+l16]
    h16x8 w0f[2][2];   // 16 VGPRs (k >= 40 rows zero)
    h16x8 w1f[4][2];   // 32 VGPRs
    h16x8 w2f[4];      // 16 VGPRs (L2 B-frags, R4 orientation)
    f32x4 b0v[2], b1v[2];   // acc-init biases, C-layout (lane owns feats q*4+r)
    float b2s;

    #pragma unroll
    for (int ks = 0; ks < 2; ++ks)
      #pragma unroll
      for (int mt = 0; mt < 2; ++mt) {
        const int n = fb + mt * 16 + l16;
        #pragma unroll
        for (int t = 0; t < 8; ++t) {
          const int k = ks * 32 + q * 8 + t;
          w0f[ks][mt][t] = (_Float16)((k < DIN) ? W0j[k * HH + n] : 0.f);
        }
      }
    #pragma unroll
    for (int ks = 0; ks < 4; ++ks)
      #pragma unroll
      for (int mt = 0; mt < 2; ++mt) {
        const int n = fb + mt * 16 + l16;
        #pragma unroll
        for (int t = 0; t < 8; ++t) {
          const int k = ks * 32 + q * 8 + t;
          w1f[ks][mt][t] = (_Float16)W1j[k * HH + n];
        }
      }
    #pragma unroll
    for (int ks = 0; ks < 4; ++ks) {
        const int n = l2n + l16;
        #pragma unroll
        for (int t = 0; t < 8; ++t) {
          const int k = ks * 32 + q * 8 + t;
          w2f[ks][t] = (_Float16)W2j[k * DS + n];
        }
    }
    #pragma unroll
    for (int mt = 0; mt < 2; ++mt)
      #pragma unroll
      for (int r = 0; r < 4; ++r) {
        b0v[mt][r] = b0g[j * HH + fb + mt * 16 + q * 4 + r];
        b1v[mt][r] = b1g[j * HH + fb + mt * 16 + q * 4 + r];
      }
    b2s = b2g[j * DS + l2n + l16];

    const f32x4 z4 = {0.f, 0.f, 0.f, 0.f};

    // staging geometry (constant across i and bt)
    const int srow = tid >> 2;        // states: row 0..63
    const int scb  = tid & 3;         // states: k-block 0..3
    const int soff = srow * DS + scb * 8;          // f32 offset within slice
    unsigned short* const sdst = &sIn[sin_idx(srow, scb)];
    unsigned short* const adst = &sIn[sin_idx(lane, 4)];   // wave 0 only

    for (int bt = slot; bt < NB / BT; bt += NSLOT) {
        const int b0 = bt * BT;

        // ---- stage inp[0] (vectorized). Safe: last sIn reads of the previous
        // bt (L0 i=7) completed before its B2; epilogue touches no LDS.
        {
            const float4* sp = reinterpret_cast<const float4*>(
                states + (size_t)b0 * DS + soff);
            const float4 f0 = sp[0], f1 = sp[1];
            uint4 pk;
            pk.x = pkh(f0.x, f0.y); pk.y = pkh(f0.z, f0.w);
            pk.z = pkh(f1.x, f1.y); pk.w = pkh(f1.z, f1.w);
            *reinterpret_cast<uint4*>(sdst) = pk;
            if (tid < BT) {
                const float4* ap = reinterpret_cast<const float4*>(
                    actions + ((size_t)b0 + lane) * DA);
                const float4 a0 = ap[0], a1 = ap[1];
                uint4 apk;
                apk.x = pkh(a0.x, a0.y); apk.y = pkh(a0.z, a0.w);
                apk.z = pkh(a1.x, a1.y); apk.w = pkh(a1.z, a1.w);
                *reinterpret_cast<uint4*>(adst) = apk;
            }
        }
        __syncthreads();

        float sa[2][4], sq[2][4];
        #pragma unroll
        for (int mt = 0; mt < 2; ++mt)
          #pragma unroll
          for (int r = 0; r < 4; ++r) { sa[mt][r] = 0.f; sq[mt][r] = 0.f; }

        for (int i = 0; i < NE; ++i) {
            // ---- Layer 0: h0 = lrelu(W0^T inp + b0); acc init = b0 ----
            #pragma unroll
            for (int nh = 0; nh < 2; ++nh) {          // batch halves
                f32x4 acc[2][2];
                #pragma unroll
                for (int mt = 0; mt < 2; ++mt)
                  #pragma unroll
                  for (int nt = 0; nt < 2; ++nt) acc[mt][nt] = b0v[mt];
                #pragma unroll
                for (int ks = 0; ks < 2; ++ks) {
                    h16x8 bf[2];
                    #pragma unroll
                    for (int nt = 0; nt < 2; ++nt) {
                        const int row = nh * 32 + nt * 16 + l16;   // B: n = lane&15
                        bf[nt] = *(const h16x8*)(&sIn[sin_idx(row, ks * 4 + q)]);
                    }
                    #pragma unroll
                    for (int mt = 0; mt < 2; ++mt)
                      #pragma unroll
                      for (int nt = 0; nt < 2; ++nt)
                        acc[mt][nt] = __builtin_amdgcn_mfma_f32_16x16x32_f16(
                            w0f[ks][mt], bf[nt], acc[mt][nt], 0, 0, 0);
                }
                // lane holds 4 consecutive features (q*4+r) of batch row nt*16+l16
                #pragma unroll
                for (int mt = 0; mt < 2; ++mt)
                  #pragma unroll
                  for (int nt = 0; nt < 2; ++nt) {
                    const int row = nh * 32 + nt * 16 + l16;
                    const int blk = (fb >> 3) + mt * 2 + (q >> 1);
                    const int idx = sh_idx(row, blk) + (q & 1) * 4;
                    uint2 pk;
                    pk.x = pklr(acc[mt][nt][0], acc[mt][nt][1]);
                    pk.y = pklr(acc[mt][nt][2], acc[mt][nt][3]);
                    *reinterpret_cast<uint2*>(&sHa[idx]) = pk;
                  }
            }
            __syncthreads();   // B2: h0 ready; sIn reads drained

            // ---- stage inp[i+1] (overlaps L1; writes blocks 0..4 only) ----
            if (i < NE - 1) {
                const float4* sp = reinterpret_cast<const float4*>(
                    states + ((size_t)(i + 1) * NB + b0) * DS + soff);
                const float4 f0 = sp[0], f1 = sp[1];
                uint4 pk;
                pk.x = pkh(f0.x, f0.y); pk.y = pkh(f0.z, f0.w);
                pk.z = pkh(f1.x, f1.y); pk.w = pkh(f1.z, f1.w);
                *reinterpret_cast<uint4*>(sdst) = pk;
                if (tid < BT) {
                    const float4* ap = reinterpret_cast<const float4*>(
                        actions + ((size_t)(i + 1) * NB + b0 + lane) * DA);
                    const float4 a0 = ap[0], a1 = ap[1];
                    uint4 apk;
                    apk.x = pkh(a0.x, a0.y); apk.y = pkh(a0.z, a0.w);
                    apk.z = pkh(a1.x, a1.y); apk.w = pkh(a1.z, a1.w);
                    *reinterpret_cast<uint4*>(adst) = apk;
                }
            }

            // ---- Layer 1: h1 = lrelu(W1^T h0 + b1); acc init = b1 ----
            #pragma unroll
            for (int nh = 0; nh < 2; ++nh) {
                f32x4 acc[2][2];
                #pragma unroll
                for (int mt = 0; mt < 2; ++mt)
                  #pragma unroll
                  for (int nt = 0; nt < 2; ++nt) acc[mt][nt] = b1v[mt];
                #pragma unroll
                for (int ks = 0; ks < 4; ++ks) {
                    h16x8 bf[2];
                    #pragma unroll
                    for (int nt = 0; nt < 2; ++nt) {
                        const int row = nh * 32 + nt * 16 + l16;
                        bf[nt] = *(const h16x8*)(&sHa[sh_idx(row, ks * 4 + q)]);
                    }
                    #pragma unroll
                    for (int mt = 0; mt < 2; ++mt)
                      #pragma unroll
                      for (int nt = 0; nt < 2; ++nt)
                        acc[mt][nt] = __builtin_amdgcn_mfma_f32_16x16x32_f16(
                            w1f[ks][mt], bf[nt], acc[mt][nt], 0, 0, 0);
                }
                #pragma unroll
                for (int mt = 0; mt < 2; ++mt)
                  #pragma unroll
                  for (int nt = 0; nt < 2; ++nt) {
                    const int row = nh * 32 + nt * 16 + l16;
                    const int blk = (fb >> 3) + mt * 2 + (q >> 1);
                    const int idx = sh_idx(row, blk) + (q & 1) * 4;
                    uint2 pk;
                    pk.x = pklr(acc[mt][nt][0], acc[mt][nt][1]);
                    pk.y = pklr(acc[mt][nt][2], acc[mt][nt][3]);
                    *reinterpret_cast<uint2*>(&sHb[idx]) = pk;
                  }
            }
            __syncthreads();   // B3: h1 + sIn(i+1) ready

            // ---- Layer 2 (R4 orientation): A=h1 (m=batch), B=W2 (n=feature) ----
            {
                f32x4 acc2[2];
                acc2[0] = z4; acc2[1] = z4;
                #pragma unroll
                for (int ks = 0; ks < 4; ++ks) {
                    #pragma unroll
                    for (int mt = 0; mt < 2; ++mt) {
                        const int row = l2m + 16 * mt + l16;
                        const h16x8 a2 = *(const h16x8*)(&sHb[sh_idx(row, ks * 4 + q)]);
                        acc2[mt] = __builtin_amdgcn_mfma_f32_16x16x32_f16(
                            a2, w2f[ks], acc2[mt], 0, 0, 0);
                    }
                }
                #pragma unroll
                for (int mt = 0; mt < 2; ++mt)
                  #pragma unroll
                  for (int r = 0; r < 4; ++r) {
                    const float a = acc2[mt][r];      // b2 deferred
                    sa[mt][r] += a;
                    sq[mt][r] = fmaf(a, a, sq[mt][r]);
                  }
            }
        }

        // ---- Epilogue for this bt: sum = sa + 8b; sum(p^2) = sq + 2b*sa + 8b^2
        #pragma unroll
        for (int mt = 0; mt < 2; ++mt)
          #pragma unroll
          for (int r = 0; r < 4; ++r) {
            const int row = l2m + 16 * mt + q * 4 + r;   // batch row (C: row=quad*4+r)
            const int col = l2n + l16;                   // feature
            const size_t o = ((size_t)j * NB + b0 + row) * DS + col;
            const float b  = b2s;
            const float s  = sa[mt][r] + 8.f * b;
            const float s2 = sq[mt][r] + 2.f * b * sa[mt][r] + 8.f * b * b;
            out[o] = s * 0.125f + states[o];
            out[(size_t)NE * NB * DS + o] = (s2 - s * s * 0.125f) * (1.0f / 7.0f);
          }
    }
}

extern "C" void kernel_launch(void* const* d_in, const int* in_sizes, int n_in,
                              void* d_out, int out_size, void* d_ws, size_t ws_size,
                              hipStream_t stream) {
    (void)in_sizes; (void)n_in; (void)d_ws; (void)ws_size; (void)out_size;
    const float* states  = (const float*)d_in[0];
    const float* actions = (const float*)d_in[1];
    const float* W0 = (const float*)d_in[2];
    const float* b0 = (const float*)d_in[3];
    const float* W1 = (const float*)d_in[4];
    const float* b1 = (const float*)d_in[5];
    const float* W2 = (const float*)d_in[6];
    const float* b2 = (const float*)d_in[7];
    float* out = (float*)d_out;
    dim3 grid(8 * NSLOT);   // 768 persistent blocks = 3/CU, one generation
    ens_mlp_kernel<<<grid, dim3(256), 0, stream>>>(states, actions, W0, b0, W1, b1, W2, b2, out);
}